// Round 2
// baseline (234.247 us; speedup 1.0000x reference)
//
#include <hip/hip_runtime.h>
#include <math.h>

#define DIM 256
#define BATCH 16
#define NO 64
#define NI 512
#define NEG_SLOPE 0.01f

// ---------------------------------------------------------------------------
// Kernel 1: projections.
//   qp[r, h] = sum_d q[r, d] * W1[h, d]        + b1[h]   (r = b*64+o, 1024 rows)
//   kp[r, h] = sum_d k[r, d] * W1[h, 256 + d]            (r = b*512+i, 8192 rows)
// Tiled FP32 GEMM: TM rows x 256 cols per block, k-chunks of TK staged in LDS.
// ---------------------------------------------------------------------------
#define TM 16
#define TK 32

__global__ __launch_bounds__(256) void proj_kernel(
    const float* __restrict__ q, const float* __restrict__ k,
    const float* __restrict__ W1, const float* __restrict__ b1,
    float* __restrict__ qp, float* __restrict__ kp)
{
  __shared__ float As[TM][TK];          // input rows chunk (broadcast reads)
  __shared__ float Ws[256][TK + 4];     // W1 chunk, +4 pad to spread banks

  const int t = threadIdx.x;
  const int r0 = blockIdx.x * TM;
  const bool isq = (r0 < BATCH * NO);
  const float* src = isq ? (q + (size_t)r0 * DIM)
                         : (k + (size_t)(r0 - BATCH * NO) * DIM);
  const int coff = isq ? 0 : DIM;

  float acc[TM];
#pragma unroll
  for (int r = 0; r < TM; ++r) acc[r] = 0.f;

  for (int c0 = 0; c0 < DIM; c0 += TK) {
    __syncthreads();
    // stage A: TM x TK floats = TM*TK/4 float4 (128 for 16x32)
    {
      const int nf4 = TM * TK / 4;
      if (t < nf4) {
        int row = t / (TK / 4);
        int j   = t % (TK / 4);
        float4 val = *(const float4*)(src + (size_t)row * DIM + c0 + j * 4);
        *(float4*)&As[row][j * 4] = val;
      }
    }
    // stage W: 256 x TK floats = 2048 float4 -> 8 per thread
#pragma unroll
    for (int p = 0; p < (256 * TK / 4) / 256; ++p) {
      int idx = t + p * 256;
      int row = idx / (TK / 4);
      int j   = idx % (TK / 4);
      float4 val = *(const float4*)(W1 + (size_t)row * (2 * DIM) + coff + c0 + j * 4);
      *(float4*)&Ws[row][j * 4] = val;
    }
    __syncthreads();
#pragma unroll
    for (int d4 = 0; d4 < TK / 4; ++d4) {
      float4 w = *(const float4*)&Ws[t][d4 * 4];
#pragma unroll
      for (int r = 0; r < TM; ++r) {
        float4 a = *(const float4*)&As[r][d4 * 4];
        acc[r] += a.x * w.x + a.y * w.y + a.z * w.z + a.w * w.w;
      }
    }
  }

  const float bias = isq ? b1[t] : 0.f;
#pragma unroll
  for (int r = 0; r < TM; ++r) {
    float val = acc[r] + bias;
    if (isq) qp[(size_t)(r0 + r) * DIM + t] = val;
    else     kp[(size_t)(r0 - BATCH * NO + r) * DIM + t] = val;
  }
}

// ---------------------------------------------------------------------------
// fast tanh: tanh(x) = 1 - 2/(exp2(x * 2*log2(e)) + 1)
// exact saturation at +/-inf of exp2; native v_exp_f32 + v_rcp_f32.
// ---------------------------------------------------------------------------
__device__ __forceinline__ float tanh_fast(float x) {
  float e = __builtin_amdgcn_exp2f(x * 2.88539008177792681f);
  return 1.0f - 2.0f * __builtin_amdgcn_rcpf(e + 1.0f);
}

// ---------------------------------------------------------------------------
// Kernel 2: one block (256 threads) per (b, o):
//   scores (2 i's per thread) -> softmax -> attn out -> PV -> Wf proj + leaky
// ---------------------------------------------------------------------------
__global__ __launch_bounds__(256) void attn_kernel(
    const float* __restrict__ qp, const float* __restrict__ kp,
    const float* __restrict__ v, const int* __restrict__ mask,
    const float* __restrict__ W2, const float* __restrict__ b2,
    const float* __restrict__ Wf, const float* __restrict__ bf,
    float* __restrict__ out, float* __restrict__ attn_out)
{
  __shared__ float qb[DIM];
  __shared__ float w2s[DIM];
  __shared__ float sc[NI];     // attn weights
  __shared__ float o0[DIM];    // pre-projection output
  __shared__ float red[4];

  const int t  = threadIdx.x;
  const int bo = blockIdx.x;           // b*64 + o
  const int b  = bo >> 6;

  qb[t]  = qp[(size_t)bo * DIM + t];
  w2s[t] = W2[t];
  __syncthreads();

  const float b2v = b2[0];

  // ---- phase 1: scores for i = t and i = t + 256 ----
  float s_local[2];
#pragma unroll
  for (int ii = 0; ii < 2; ++ii) {
    const int i = t + ii * 256;
    const float4* kr = (const float4*)(kp + ((size_t)b * NI + i) * DIM);
    const float4* q4 = (const float4*)qb;
    const float4* w4 = (const float4*)w2s;
    float acc = 0.f;
#pragma unroll 4
    for (int h4 = 0; h4 < DIM / 4; ++h4) {
      float4 kv = kr[h4];
      float4 qv = q4[h4];
      float4 wv = w4[h4];
      acc += wv.x * tanh_fast(qv.x + kv.x);
      acc += wv.y * tanh_fast(qv.y + kv.y);
      acc += wv.z * tanh_fast(qv.z + kv.z);
      acc += wv.w * tanh_fast(qv.w + kv.w);
    }
    float s = acc + b2v;
    if (mask[b * NI + i]) s = -INFINITY;
    s_local[ii] = s;
  }

  // ---- phase 2: softmax over 512 scores ----
  const int lane = t & 63;
  const int wid  = t >> 6;

  float m = fmaxf(s_local[0], s_local[1]);
#pragma unroll
  for (int off = 32; off >= 1; off >>= 1) m = fmaxf(m, __shfl_xor(m, off, 64));
  if (lane == 0) red[wid] = m;
  __syncthreads();
  m = fmaxf(fmaxf(red[0], red[1]), fmaxf(red[2], red[3]));

  float p0 = __expf(s_local[0] - m);
  float p1 = __expf(s_local[1] - m);
  float sum = p0 + p1;
#pragma unroll
  for (int off = 32; off >= 1; off >>= 1) sum += __shfl_xor(sum, off, 64);
  __syncthreads();                 // everyone done reading red for max
  if (lane == 0) red[wid] = sum;
  __syncthreads();
  sum = (red[0] + red[1]) + (red[2] + red[3]);

  const float inv = __builtin_amdgcn_rcpf(sum);
  const float a0 = p0 * inv;
  const float a1 = p1 * inv;
  sc[t]       = a0;
  sc[t + 256] = a1;
  attn_out[(size_t)bo * NI + t]       = a0;
  attn_out[(size_t)bo * NI + t + 256] = a1;
  __syncthreads();

  // ---- phase 3: PV: o0[d] = sum_i attn[i] * v[b, i, d] ----
  {
    float acc0 = 0.f, acc1 = 0.f, acc2 = 0.f, acc3 = 0.f;
    const float* vb = v + (size_t)b * NI * DIM + t;
    for (int i = 0; i < NI; i += 4) {
      acc0 += sc[i + 0] * vb[(size_t)(i + 0) * DIM];
      acc1 += sc[i + 1] * vb[(size_t)(i + 1) * DIM];
      acc2 += sc[i + 2] * vb[(size_t)(i + 2) * DIM];
      acc3 += sc[i + 3] * vb[(size_t)(i + 3) * DIM];
    }
    o0[t] = (acc0 + acc1) + (acc2 + acc3);
  }
  __syncthreads();

  // ---- phase 4: final projection + leaky ReLU ----
  {
    const float4* wfr = (const float4*)(Wf + (size_t)t * DIM);
    const float4* o4  = (const float4*)o0;
    float f0 = 0.f, f1 = 0.f, f2 = 0.f, f3 = 0.f;
#pragma unroll 4
    for (int d4 = 0; d4 < DIM / 4; ++d4) {
      float4 wv = wfr[d4];
      float4 ov = o4[d4];
      f0 += wv.x * ov.x;
      f1 += wv.y * ov.y;
      f2 += wv.z * ov.z;
      f3 += wv.w * ov.w;
    }
    float f = ((f0 + f1) + (f2 + f3)) + bf[t];
    f = (f >= 0.f) ? f : NEG_SLOPE * f;
    out[(size_t)bo * DIM + t] = f;
  }
}

// ---------------------------------------------------------------------------
extern "C" void kernel_launch(void* const* d_in, const int* in_sizes, int n_in,
                              void* d_out, int out_size, void* d_ws, size_t ws_size,
                              hipStream_t stream) {
  const float* q    = (const float*)d_in[0];
  const float* k    = (const float*)d_in[1];
  const float* v    = (const float*)d_in[2];
  const int*   mask = (const int*)d_in[3];
  const float* W1   = (const float*)d_in[4];
  const float* b1   = (const float*)d_in[5];
  const float* W2   = (const float*)d_in[6];
  const float* b2   = (const float*)d_in[7];
  const float* Wf   = (const float*)d_in[8];
  const float* bf   = (const float*)d_in[9];

  float* out      = (float*)d_out;                    // (16,64,256)
  float* attn_out = out + (size_t)BATCH * NO * DIM;   // (16,64,512)

  float* qp = (float*)d_ws;                           // 1024 x 256
  float* kp = qp + (size_t)BATCH * NO * DIM;          // 8192 x 256

  const int nrows = BATCH * NO + BATCH * NI;          // 9216
  proj_kernel<<<nrows / TM, 256, 0, stream>>>(q, k, W1, b1, qp, kp);
  attn_kernel<<<BATCH * NO, 256, 0, stream>>>(qp, kp, v, mask, W2, b2, Wf, bf,
                                              out, attn_out);
}

// Round 3
// 170.238 us; speedup vs baseline: 1.3760x; 1.3760x over previous
//
#include <hip/hip_runtime.h>
#include <math.h>

#define DIM 256
#define BATCH 16
#define NO 64
#define NI 512
#define NEG_SLOPE 0.01f
#define CSCALE 2.885390081777927f   // 2*log2(e): tanh(x) = 1 - 2/(exp2(CSCALE*x)+1)

// ---------------------------------------------------------------------------
// Kernel 1 (blocks 0..575): GEMM  out[r,h] = sum_d A[r,d] * W1[h, coff+d]
//   rows 0..1023   -> qp[bo][h]   = (acc + b1[h]) * CSCALE      (A = q)
//   rows 1024..9215-> kpT[b][h][i] = acc * CSCALE   (transposed; A = k)
// 64x64 tile, K-chunk 32, 4x4 microtile per thread, transposed LDS tiles.
// Kernel 1 (blocks 576..591): transpose Wf (256x256) -> WfT.
// ---------------------------------------------------------------------------
__global__ __launch_bounds__(256) void proj_kernel(
    const float* __restrict__ q, const float* __restrict__ k,
    const float* __restrict__ W1, const float* __restrict__ b1,
    const float* __restrict__ Wf,
    float* __restrict__ qp, float* __restrict__ kpT, float* __restrict__ WfT)
{
  __shared__ float smem[4352];      // 17 KB: GEMM: At[32][68] + Wt[32][68]; transpose: tile[64][68]

  const int t  = threadIdx.x;
  const int bx = blockIdx.x;

  if (bx >= 576) {
    // ---- Wf transpose: 16 tiles of 64x64 ----
    const int tt = bx - 576;
    const int tr = tt >> 2, tc = tt & 3;
#pragma unroll
    for (int p = 0; p < 4; ++p) {
      int idx = p * 256 + t;
      int row = idx >> 4, j = idx & 15;
      float4 vv = *(const float4*)(Wf + (size_t)(tr * 64 + row) * 256 + tc * 64 + j * 4);
      *(float4*)&smem[row * 68 + j * 4] = vv;
    }
    __syncthreads();
#pragma unroll
    for (int p = 0; p < 4; ++p) {
      int idx = p * 256 + t;
      int row = idx >> 4, j = idx & 15;
      float4 ov;
      ov.x = smem[(j * 4 + 0) * 68 + row];
      ov.y = smem[(j * 4 + 1) * 68 + row];
      ov.z = smem[(j * 4 + 2) * 68 + row];
      ov.w = smem[(j * 4 + 3) * 68 + row];
      *(float4*)(WfT + (size_t)(tc * 64 + row) * 256 + tr * 64 + j * 4) = ov;
    }
    return;
  }

  // ---- GEMM path ----
  float* At = smem;                 // At[dk][r],  stride 68
  float* Wt = smem + 32 * 68;       // Wt[dk][h],  stride 68

  const int tx = t & 15;            // col group (h)
  const int ty = t >> 4;            // row group (r)
  const int mt = bx >> 2;           // 0..143
  const int nt = bx & 3;            // 0..3
  const int r0 = mt * 64;
  const int h0 = nt * 64;
  const bool isq = (r0 < BATCH * NO);
  const float* src = isq ? (q + (size_t)r0 * DIM)
                         : (k + (size_t)(r0 - BATCH * NO) * DIM);
  const int coff = isq ? 0 : DIM;

  float acc[4][4] = {};

  for (int c0 = 0; c0 < DIM; c0 += 32) {
    __syncthreads();
#pragma unroll
    for (int p = 0; p < 2; ++p) {
      int idx = p * 256 + t;
      int row = idx >> 3, j = idx & 7;       // row 0..63, j 0..7
      float4 av = *(const float4*)(src + (size_t)row * DIM + c0 + j * 4);
      At[(4 * j + 0) * 68 + row] = av.x;
      At[(4 * j + 1) * 68 + row] = av.y;
      At[(4 * j + 2) * 68 + row] = av.z;
      At[(4 * j + 3) * 68 + row] = av.w;
      float4 wv = *(const float4*)(W1 + (size_t)(h0 + row) * (2 * DIM) + coff + c0 + j * 4);
      Wt[(4 * j + 0) * 68 + row] = wv.x;
      Wt[(4 * j + 1) * 68 + row] = wv.y;
      Wt[(4 * j + 2) * 68 + row] = wv.z;
      Wt[(4 * j + 3) * 68 + row] = wv.w;
    }
    __syncthreads();
#pragma unroll
    for (int dk = 0; dk < 32; ++dk) {
      float4 a4 = *(const float4*)&At[dk * 68 + ty * 4];
      float4 w4 = *(const float4*)&Wt[dk * 68 + tx * 4];
      const float ar[4] = {a4.x, a4.y, a4.z, a4.w};
      const float wr[4] = {w4.x, w4.y, w4.z, w4.w};
#pragma unroll
      for (int rr = 0; rr < 4; ++rr)
#pragma unroll
        for (int cc = 0; cc < 4; ++cc)
          acc[rr][cc] = fmaf(ar[rr], wr[cc], acc[rr][cc]);
    }
  }

  if (isq) {
    float4 bv = *(const float4*)(b1 + h0 + tx * 4);
    const float br[4] = {bv.x, bv.y, bv.z, bv.w};
#pragma unroll
    for (int rr = 0; rr < 4; ++rr) {
      int r = r0 + ty * 4 + rr;
      float4 ov;
      ov.x = (acc[rr][0] + br[0]) * CSCALE;
      ov.y = (acc[rr][1] + br[1]) * CSCALE;
      ov.z = (acc[rr][2] + br[2]) * CSCALE;
      ov.w = (acc[rr][3] + br[3]) * CSCALE;
      *(float4*)(qp + (size_t)r * DIM + h0 + tx * 4) = ov;
    }
  } else {
    int ig0 = r0 - BATCH * NO;
    int b  = ig0 >> 9;                 // tile never crosses a b boundary (64 | 512)
    int i0 = (ig0 & 511) + ty * 4;
#pragma unroll
    for (int cc = 0; cc < 4; ++cc) {
      int h = h0 + tx * 4 + cc;
      float4 ov;
      ov.x = acc[0][cc] * CSCALE;
      ov.y = acc[1][cc] * CSCALE;
      ov.z = acc[2][cc] * CSCALE;
      ov.w = acc[3][cc] * CSCALE;
      *(float4*)(kpT + ((size_t)(b * 256 + h)) * NI + i0) = ov;
    }
  }
}

// ---------------------------------------------------------------------------
// Kernel 2: one block (256 threads) per (b,o), XCD-swizzled.
// phase 1: scores for i=2t,2t+1 via coalesced kpT float2 reads
// phase 2: softmax;  phase 3: PV (4 i-splits x float4-over-d);  phase 4: WfT proj
// ---------------------------------------------------------------------------
__global__ __launch_bounds__(256) void attn_kernel(
    const float* __restrict__ qp, const float* __restrict__ kpT,
    const float* __restrict__ v, const int* __restrict__ mask,
    const float* __restrict__ W2, const float* __restrict__ b2,
    const float* __restrict__ WfT, const float* __restrict__ bf,
    float* __restrict__ out, float* __restrict__ attn_out)
{
  __shared__ float qb[DIM];
  __shared__ float w2s[DIM];
  __shared__ float sc[NI];
  __shared__ float o0[DIM];
  __shared__ float pv_part[4][DIM];
  __shared__ float red[4];

  const int t   = threadIdx.x;
  const int blk = blockIdx.x;
  const int bo  = (blk & 7) * 128 + (blk >> 3);   // XCD swizzle: same-b blocks share an XCD
  const int b   = bo >> 6;

  const float myw = W2[t];
  qb[t]  = qp[(size_t)bo * DIM + t];
  w2s[t] = myw;
  __syncthreads();

  const int lane = t & 63;
  const int wid  = t >> 6;

  // sumW2 (once per block)
  float sw = myw;
#pragma unroll
  for (int off = 32; off >= 1; off >>= 1) sw += __shfl_xor(sw, off, 64);
  if (lane == 0) red[wid] = sw;
  __syncthreads();
  const float sumw2 = (red[0] + red[1]) + (red[2] + red[3]);
  const float b2v = b2[0];

  // ---- phase 1: scores for i = 2t, 2t+1 ----
  float s0acc = 0.f, s1acc = 0.f;
  const float2* kb = (const float2*)(kpT + (size_t)b * 256 * NI);   // kb[h*256 + t]
#pragma unroll 2
  for (int h4 = 0; h4 < 64; ++h4) {
    float4 qv4 = *(const float4*)&qb[h4 * 4];
    float4 wv4 = *(const float4*)&w2s[h4 * 4];
    const float qr[4] = {qv4.x, qv4.y, qv4.z, qv4.w};
    const float wr[4] = {wv4.x, wv4.y, wv4.z, wv4.w};
#pragma unroll
    for (int e = 0; e < 4; ++e) {
      int h = h4 * 4 + e;
      float2 kv = kb[h * 256 + t];
      float e0 = __builtin_amdgcn_exp2f(qr[e] + kv.x);
      float e1 = __builtin_amdgcn_exp2f(qr[e] + kv.y);
      s0acc = fmaf(wr[e], __builtin_amdgcn_rcpf(e0 + 1.f), s0acc);
      s1acc = fmaf(wr[e], __builtin_amdgcn_rcpf(e1 + 1.f), s1acc);
    }
  }
  const int2 mm = ((const int2*)(mask + (size_t)b * NI))[t];
  float s0 = sumw2 - 2.f * s0acc + b2v;
  float s1 = sumw2 - 2.f * s1acc + b2v;
  if (mm.x) s0 = -INFINITY;
  if (mm.y) s1 = -INFINITY;

  // ---- phase 2: softmax over 512 ----
  __syncthreads();                 // sumw2 reads done; red reusable
  float m = fmaxf(s0, s1);
#pragma unroll
  for (int off = 32; off >= 1; off >>= 1) m = fmaxf(m, __shfl_xor(m, off, 64));
  if (lane == 0) red[wid] = m;
  __syncthreads();
  m = fmaxf(fmaxf(red[0], red[1]), fmaxf(red[2], red[3]));

  float p0 = __expf(s0 - m);
  float p1 = __expf(s1 - m);
  float sum = p0 + p1;
#pragma unroll
  for (int off = 32; off >= 1; off >>= 1) sum += __shfl_xor(sum, off, 64);
  __syncthreads();
  if (lane == 0) red[wid] = sum;
  __syncthreads();
  sum = (red[0] + red[1]) + (red[2] + red[3]);

  const float inv = __builtin_amdgcn_rcpf(sum);
  const float a0 = p0 * inv;
  const float a1 = p1 * inv;
  ((float2*)sc)[t] = make_float2(a0, a1);
  ((float2*)(attn_out + (size_t)bo * NI))[t] = make_float2(a0, a1);
  __syncthreads();

  // ---- phase 3: PV. wave w handles i in [w*128, w*128+128), lane d4 = 4 d's ----
  {
    const int d4  = t & 63;
    const int isp = t >> 6;
    float4 accv = {0.f, 0.f, 0.f, 0.f};
    const float4* vb4 = (const float4*)(v + (size_t)b * NI * DIM);
#pragma unroll 4
    for (int i = isp * 128; i < isp * 128 + 128; ++i) {
      float s = sc[i];
      float4 vv = vb4[(size_t)i * 64 + d4];
      accv.x = fmaf(s, vv.x, accv.x);
      accv.y = fmaf(s, vv.y, accv.y);
      accv.z = fmaf(s, vv.z, accv.z);
      accv.w = fmaf(s, vv.w, accv.w);
    }
    *(float4*)&pv_part[isp][d4 * 4] = accv;
  }
  __syncthreads();
  o0[t] = (pv_part[0][t] + pv_part[1][t]) + (pv_part[2][t] + pv_part[3][t]);
  __syncthreads();

  // ---- phase 4: out[d] = leaky(sum_e o0[e]*WfT[e][d] + bf[d]) ----
  {
    float f = 0.f;
#pragma unroll 8
    for (int e = 0; e < DIM; ++e) {
      f = fmaf(o0[e], WfT[(size_t)e * DIM + t], f);
    }
    f += bf[t];
    f = (f >= 0.f) ? f : NEG_SLOPE * f;
    out[(size_t)bo * DIM + t] = f;
  }
}

// ---------------------------------------------------------------------------
extern "C" void kernel_launch(void* const* d_in, const int* in_sizes, int n_in,
                              void* d_out, int out_size, void* d_ws, size_t ws_size,
                              hipStream_t stream) {
  const float* q    = (const float*)d_in[0];
  const float* k    = (const float*)d_in[1];
  const float* v    = (const float*)d_in[2];
  const int*   mask = (const int*)d_in[3];
  const float* W1   = (const float*)d_in[4];
  const float* b1   = (const float*)d_in[5];
  const float* W2   = (const float*)d_in[6];
  const float* b2   = (const float*)d_in[7];
  const float* Wf   = (const float*)d_in[8];
  const float* bf   = (const float*)d_in[9];

  float* out      = (float*)d_out;                    // (16,64,256)
  float* attn_out = out + (size_t)BATCH * NO * DIM;   // (16,64,512)

  float* qp  = (float*)d_ws;                          // 1024 x 256 (scaled, +b1)
  float* kpT = qp + (size_t)BATCH * NO * DIM;         // 16 x 256 x 512 (scaled)
  float* WfT = kpT + (size_t)BATCH * DIM * NI;        // 256 x 256

  proj_kernel<<<592, 256, 0, stream>>>(q, k, W1, b1, Wf, qp, kpT, WfT);
  attn_kernel<<<BATCH * NO, 256, 0, stream>>>(qp, kpT, v, mask, W2, b2, WfT, bf,
                                              out, attn_out);
}

// Round 4
// 163.703 us; speedup vs baseline: 1.4309x; 1.0399x over previous
//
#include <hip/hip_runtime.h>
#include <math.h>

#define DIM 256
#define BATCH 16
#define NO 64
#define NI 512
#define NEG_SLOPE 0.01f
#define CSCALE 2.885390081777927f   // 2*log2(e): tanh(x) = 1 - 2/(exp2(CSCALE*x)+1)
#define OT 4                        // o's per attn block

// ---------------------------------------------------------------------------
// Kernel 1 (blocks 0..575): GEMM  out[r,h] = sum_d A[r,d] * W1[h, coff+d]
//   rows 0..1023   -> qp[bo][h]    = (acc + b1[h]) * CSCALE     (A = q)
//   rows 1024..9215-> kpT[b][h][i] = acc * CSCALE  (transposed; A = k)
// 64x64 tile, K-chunk 32, 4x4 microtile per thread, transposed LDS tiles.
// Blocks 576..591: transpose Wf (256x256) -> WfT.
// ---------------------------------------------------------------------------
__global__ __launch_bounds__(256) void proj_kernel(
    const float* __restrict__ q, const float* __restrict__ k,
    const float* __restrict__ W1, const float* __restrict__ b1,
    const float* __restrict__ Wf,
    float* __restrict__ qp, float* __restrict__ kpT, float* __restrict__ WfT)
{
  __shared__ float smem[4352];

  const int t  = threadIdx.x;
  const int bx = blockIdx.x;

  if (bx >= 576) {
    const int tt = bx - 576;
    const int tr = tt >> 2, tc = tt & 3;
#pragma unroll
    for (int p = 0; p < 4; ++p) {
      int idx = p * 256 + t;
      int row = idx >> 4, j = idx & 15;
      float4 vv = *(const float4*)(Wf + (size_t)(tr * 64 + row) * 256 + tc * 64 + j * 4);
      *(float4*)&smem[row * 68 + j * 4] = vv;
    }
    __syncthreads();
#pragma unroll
    for (int p = 0; p < 4; ++p) {
      int idx = p * 256 + t;
      int row = idx >> 4, j = idx & 15;
      float4 ov;
      ov.x = smem[(j * 4 + 0) * 68 + row];
      ov.y = smem[(j * 4 + 1) * 68 + row];
      ov.z = smem[(j * 4 + 2) * 68 + row];
      ov.w = smem[(j * 4 + 3) * 68 + row];
      *(float4*)(WfT + (size_t)(tc * 64 + row) * 256 + tr * 64 + j * 4) = ov;
    }
    return;
  }

  float* At = smem;
  float* Wt = smem + 32 * 68;

  const int tx = t & 15;
  const int ty = t >> 4;
  const int mt = bx >> 2;
  const int nt = bx & 3;
  const int r0 = mt * 64;
  const int h0 = nt * 64;
  const bool isq = (r0 < BATCH * NO);
  const float* src = isq ? (q + (size_t)r0 * DIM)
                         : (k + (size_t)(r0 - BATCH * NO) * DIM);
  const int coff = isq ? 0 : DIM;

  float acc[4][4] = {};

  for (int c0 = 0; c0 < DIM; c0 += 32) {
    __syncthreads();
#pragma unroll
    for (int p = 0; p < 2; ++p) {
      int idx = p * 256 + t;
      int row = idx >> 3, j = idx & 7;
      float4 av = *(const float4*)(src + (size_t)row * DIM + c0 + j * 4);
      At[(4 * j + 0) * 68 + row] = av.x;
      At[(4 * j + 1) * 68 + row] = av.y;
      At[(4 * j + 2) * 68 + row] = av.z;
      At[(4 * j + 3) * 68 + row] = av.w;
      float4 wv = *(const float4*)(W1 + (size_t)(h0 + row) * (2 * DIM) + coff + c0 + j * 4);
      Wt[(4 * j + 0) * 68 + row] = wv.x;
      Wt[(4 * j + 1) * 68 + row] = wv.y;
      Wt[(4 * j + 2) * 68 + row] = wv.z;
      Wt[(4 * j + 3) * 68 + row] = wv.w;
    }
    __syncthreads();
#pragma unroll
    for (int dk = 0; dk < 32; ++dk) {
      float4 a4 = *(const float4*)&At[dk * 68 + ty * 4];
      float4 w4 = *(const float4*)&Wt[dk * 68 + tx * 4];
      const float ar[4] = {a4.x, a4.y, a4.z, a4.w};
      const float wr[4] = {w4.x, w4.y, w4.z, w4.w};
#pragma unroll
      for (int rr = 0; rr < 4; ++rr)
#pragma unroll
        for (int cc = 0; cc < 4; ++cc)
          acc[rr][cc] = fmaf(ar[rr], wr[cc], acc[rr][cc]);
    }
  }

  if (isq) {
    float4 bv = *(const float4*)(b1 + h0 + tx * 4);
    const float br[4] = {bv.x, bv.y, bv.z, bv.w};
#pragma unroll
    for (int rr = 0; rr < 4; ++rr) {
      int r = r0 + ty * 4 + rr;
      float4 ov;
      ov.x = (acc[rr][0] + br[0]) * CSCALE;
      ov.y = (acc[rr][1] + br[1]) * CSCALE;
      ov.z = (acc[rr][2] + br[2]) * CSCALE;
      ov.w = (acc[rr][3] + br[3]) * CSCALE;
      *(float4*)(qp + (size_t)r * DIM + h0 + tx * 4) = ov;
    }
  } else {
    int ig0 = r0 - BATCH * NO;
    int b  = ig0 >> 9;
    int i0 = (ig0 & 511) + ty * 4;
#pragma unroll
    for (int cc = 0; cc < 4; ++cc) {
      int h = h0 + tx * 4 + cc;
      float4 ov;
      ov.x = acc[0][cc] * CSCALE;
      ov.y = acc[1][cc] * CSCALE;
      ov.z = acc[2][cc] * CSCALE;
      ov.w = acc[3][cc] * CSCALE;
      *(float4*)(kpT + ((size_t)(b * 256 + h)) * NI + i0) = ov;
    }
  }
}

__device__ __forceinline__ void f4arr(float4 v, float* a) {
  a[0] = v.x; a[1] = v.y; a[2] = v.z; a[3] = v.w;
}

// ---------------------------------------------------------------------------
// Kernel 2: one block (512 threads) per (b, o-tile of 4). XCD-swizzled so each
// XCD sees only 2 b's (kp+v slice 2 MB < 4 MB L2).
// phase 1: thread = one i, 4 o's; kp coalesced dword loads; q/W2 wave-uniform
//          (scalar-cache) loads; algebraic tanh fold (exp2+rcp).
// phase 2: 4 softmaxes batched over the block.
// phase 3: PV with v read ONCE per block, partials in LDS.
// phase 4: WfT column shared across 2 o's per thread.
// ---------------------------------------------------------------------------
__global__ __launch_bounds__(512) void attn_kernel(
    const float* __restrict__ qp, const float* __restrict__ kpT,
    const float* __restrict__ v, const int* __restrict__ mask,
    const float* __restrict__ W2, const float* __restrict__ b2,
    const float* __restrict__ WfT, const float* __restrict__ bf,
    float* __restrict__ out, float* __restrict__ attn_out)
{
  __shared__ float sc[OT][NI];        // 8 KB
  __shared__ float pvp[8][OT][DIM];   // 32 KB
  __shared__ float o0[OT][DIM];       // 4 KB
  __shared__ float red4[8][OT];
  __shared__ float redw[8];

  const int t    = threadIdx.x;
  const int lane = t & 63;
  const int wid  = t >> 6;

  const int blk  = blockIdx.x;
  const int tile = (blk & 7) * 32 + (blk >> 3);   // XCD swizzle
  const int b    = tile >> 4;
  const int bo0  = b * 64 + (tile & 15) * OT;

  // ---- sumW2 (once per block) ----
  float partial = (t < DIM) ? W2[t] : 0.f;
#pragma unroll
  for (int off = 32; off >= 1; off >>= 1) partial += __shfl_xor(partial, off, 64);
  if (lane == 0) redw[wid] = partial;
  __syncthreads();
  float sumw2 = 0.f;
#pragma unroll
  for (int w = 0; w < 8; ++w) sumw2 += redw[w];
  const float base = sumw2 + b2[0];

  // ---- phase 1: scores s[oo] for i = t ----
  const int i = t;
  const float* kb = kpT + (size_t)b * DIM * NI;
  const float* qrow0 = qp + (size_t)(bo0 + 0) * DIM;
  const float* qrow1 = qp + (size_t)(bo0 + 1) * DIM;
  const float* qrow2 = qp + (size_t)(bo0 + 2) * DIM;
  const float* qrow3 = qp + (size_t)(bo0 + 3) * DIM;

  float acc[OT] = {0.f, 0.f, 0.f, 0.f};
#pragma unroll 2
  for (int h4 = 0; h4 < 64; ++h4) {
    float wr[4], qr[OT][4], kv[4];
    f4arr(*(const float4*)(W2 + h4 * 4), wr);        // wave-uniform -> s_load
    f4arr(*(const float4*)(qrow0 + h4 * 4), qr[0]);
    f4arr(*(const float4*)(qrow1 + h4 * 4), qr[1]);
    f4arr(*(const float4*)(qrow2 + h4 * 4), qr[2]);
    f4arr(*(const float4*)(qrow3 + h4 * 4), qr[3]);
#pragma unroll
    for (int e = 0; e < 4; ++e) kv[e] = kb[(size_t)(h4 * 4 + e) * NI + i];
#pragma unroll
    for (int e = 0; e < 4; ++e) {
#pragma unroll
      for (int oo = 0; oo < OT; ++oo) {
        float ex = __builtin_amdgcn_exp2f(qr[oo][e] + kv[e]);
        acc[oo] = fmaf(wr[e], __builtin_amdgcn_rcpf(ex + 1.f), acc[oo]);
      }
    }
  }

  const int mv = mask[(size_t)b * NI + i];
  float s[OT];
#pragma unroll
  for (int oo = 0; oo < OT; ++oo) {
    s[oo] = base - 2.f * acc[oo];
    if (mv) s[oo] = -INFINITY;
  }

  // ---- phase 2: 4 softmaxes over 512 lanes ----
  float m[OT];
#pragma unroll
  for (int oo = 0; oo < OT; ++oo) {
    m[oo] = s[oo];
#pragma unroll
    for (int off = 32; off >= 1; off >>= 1) m[oo] = fmaxf(m[oo], __shfl_xor(m[oo], off, 64));
  }
  __syncthreads();     // redw reads done; red4 safe to write
  if (lane == 0) {
#pragma unroll
    for (int oo = 0; oo < OT; ++oo) red4[wid][oo] = m[oo];
  }
  __syncthreads();
#pragma unroll
  for (int oo = 0; oo < OT; ++oo) {
    float mm = red4[0][oo];
#pragma unroll
    for (int w = 1; w < 8; ++w) mm = fmaxf(mm, red4[w][oo]);
    m[oo] = mm;
  }

  float p[OT], psum[OT];
#pragma unroll
  for (int oo = 0; oo < OT; ++oo) {
    p[oo] = __expf(s[oo] - m[oo]);
    psum[oo] = p[oo];
#pragma unroll
    for (int off = 32; off >= 1; off >>= 1) psum[oo] += __shfl_xor(psum[oo], off, 64);
  }
  __syncthreads();     // red4 (max) reads done
  if (lane == 0) {
#pragma unroll
    for (int oo = 0; oo < OT; ++oo) red4[wid][oo] = psum[oo];
  }
  __syncthreads();
#pragma unroll
  for (int oo = 0; oo < OT; ++oo) {
    float ss = 0.f;
#pragma unroll
    for (int w = 0; w < 8; ++w) ss += red4[w][oo];
    float a = p[oo] * __builtin_amdgcn_rcpf(ss);
    sc[oo][i] = a;
    attn_out[(size_t)(bo0 + oo) * NI + i] = a;
  }
  __syncthreads();

  // ---- phase 3: PV. wave wid handles i in [wid*64, wid*64+64), lane = 4 d's ----
  {
    const int d4 = lane;
    float4 av[OT];
#pragma unroll
    for (int oo = 0; oo < OT; ++oo) av[oo] = make_float4(0.f, 0.f, 0.f, 0.f);
    const float4* vb4 = (const float4*)(v + (size_t)b * NI * DIM);
    for (int ib = wid * 64; ib < wid * 64 + 64; ib += 4) {
      float sa[OT][4];
#pragma unroll
      for (int oo = 0; oo < OT; ++oo) f4arr(*(const float4*)&sc[oo][ib], sa[oo]);
#pragma unroll
      for (int j = 0; j < 4; ++j) {
        float4 vv = vb4[(size_t)(ib + j) * 64 + d4];
#pragma unroll
        for (int oo = 0; oo < OT; ++oo) {
          av[oo].x = fmaf(sa[oo][j], vv.x, av[oo].x);
          av[oo].y = fmaf(sa[oo][j], vv.y, av[oo].y);
          av[oo].z = fmaf(sa[oo][j], vv.z, av[oo].z);
          av[oo].w = fmaf(sa[oo][j], vv.w, av[oo].w);
        }
      }
    }
#pragma unroll
    for (int oo = 0; oo < OT; ++oo) *(float4*)&pvp[wid][oo][d4 * 4] = av[oo];
  }
  __syncthreads();
#pragma unroll
  for (int pp = 0; pp < 2; ++pp) {
    int flat = pp * 512 + t;
    int oo = flat >> 8, d = flat & 255;
    float sacc = 0.f;
#pragma unroll
    for (int w = 0; w < 8; ++w) sacc += pvp[w][oo][d];
    o0[oo][d] = sacc;
  }
  __syncthreads();

  // ---- phase 4: final projection + leaky ReLU. thread: d = t&255, o's {oo, oo+2} ----
  {
    const int oo = t >> 8;      // 0 or 1
    const int d  = t & 255;
    float f0 = 0.f, f1 = 0.f;
#pragma unroll 4
    for (int e4 = 0; e4 < 64; ++e4) {
      float oa[4], ob[4];
      f4arr(*(const float4*)&o0[oo][e4 * 4], oa);
      f4arr(*(const float4*)&o0[oo + 2][e4 * 4], ob);
#pragma unroll
      for (int c = 0; c < 4; ++c) {
        float wv = WfT[(size_t)(e4 * 4 + c) * DIM + d];
        f0 = fmaf(oa[c], wv, f0);
        f1 = fmaf(ob[c], wv, f1);
      }
    }
    float bfv = bf[d];
    f0 += bfv; f1 += bfv;
    f0 = (f0 >= 0.f) ? f0 : NEG_SLOPE * f0;
    f1 = (f1 >= 0.f) ? f1 : NEG_SLOPE * f1;
    out[(size_t)(bo0 + oo) * DIM + d]     = f0;
    out[(size_t)(bo0 + oo + 2) * DIM + d] = f1;
  }
}

// ---------------------------------------------------------------------------
extern "C" void kernel_launch(void* const* d_in, const int* in_sizes, int n_in,
                              void* d_out, int out_size, void* d_ws, size_t ws_size,
                              hipStream_t stream) {
  const float* q    = (const float*)d_in[0];
  const float* k    = (const float*)d_in[1];
  const float* v    = (const float*)d_in[2];
  const int*   mask = (const int*)d_in[3];
  const float* W1   = (const float*)d_in[4];
  const float* b1   = (const float*)d_in[5];
  const float* W2   = (const float*)d_in[6];
  const float* b2   = (const float*)d_in[7];
  const float* Wf   = (const float*)d_in[8];
  const float* bf   = (const float*)d_in[9];

  float* out      = (float*)d_out;                    // (16,64,256)
  float* attn_out = out + (size_t)BATCH * NO * DIM;   // (16,64,512)

  float* qp  = (float*)d_ws;                          // 1024 x 256 (scaled, +b1)
  float* kpT = qp + (size_t)BATCH * NO * DIM;         // 16 x 256 x 512 (scaled)
  float* WfT = kpT + (size_t)BATCH * DIM * NI;        // 256 x 256

  proj_kernel<<<592, 256, 0, stream>>>(q, k, W1, b1, Wf, qp, kpT, WfT);
  attn_kernel<<<(BATCH * NO) / OT, 512, 0, stream>>>(qp, kpT, v, mask, W2, b2,
                                                     WfT, bf, out, attn_out);
}

// Round 5
// 154.755 us; speedup vs baseline: 1.5137x; 1.0578x over previous
//
#include <hip/hip_runtime.h>
#include <math.h>

#define DIM 256
#define BATCH 16
#define NO 64
#define NI 512
#define NEG_SLOPE 0.01f
#define CSCALE 2.885390081777927f   // 2*log2(e): tanh(x) = 1 - 2/(exp2(CSCALE*x)+1)
#define OT 2                        // o's per attn block

// ---------------------------------------------------------------------------
// Kernel 1 (blocks 0..575): GEMM  out[r,h] = sum_d A[r,d] * W1[h, coff+d]
//   rows 0..1023    -> qp[bo][h]        = (acc + b1[h]) * CSCALE   (A = q)
//   rows 1024..9215 -> kp2[b][h/2][i]   = acc * CSCALE  (float2-pair interleave)
// 64x64 tile, K-chunk 32, 4x4 microtile per thread, transposed LDS tiles.
// Blocks 576..591: transpose Wf (256x256) -> WfT.
// ---------------------------------------------------------------------------
__global__ __launch_bounds__(256) void proj_kernel(
    const float* __restrict__ q, const float* __restrict__ k,
    const float* __restrict__ W1, const float* __restrict__ b1,
    const float* __restrict__ Wf,
    float* __restrict__ qp, float* __restrict__ kp2, float* __restrict__ WfT)
{
  __shared__ float smem[4352];

  const int t  = threadIdx.x;
  const int bx = blockIdx.x;

  if (bx >= 576) {
    const int tt = bx - 576;
    const int tr = tt >> 2, tc = tt & 3;
#pragma unroll
    for (int p = 0; p < 4; ++p) {
      int idx = p * 256 + t;
      int row = idx >> 4, j = idx & 15;
      float4 vv = *(const float4*)(Wf + (size_t)(tr * 64 + row) * 256 + tc * 64 + j * 4);
      *(float4*)&smem[row * 68 + j * 4] = vv;
    }
    __syncthreads();
#pragma unroll
    for (int p = 0; p < 4; ++p) {
      int idx = p * 256 + t;
      int row = idx >> 4, j = idx & 15;
      float4 ov;
      ov.x = smem[(j * 4 + 0) * 68 + row];
      ov.y = smem[(j * 4 + 1) * 68 + row];
      ov.z = smem[(j * 4 + 2) * 68 + row];
      ov.w = smem[(j * 4 + 3) * 68 + row];
      *(float4*)(WfT + (size_t)(tc * 64 + row) * 256 + tr * 64 + j * 4) = ov;
    }
    return;
  }

  float* At = smem;
  float* Wt = smem + 32 * 68;

  const int tx = t & 15;
  const int ty = t >> 4;
  const int mt = bx >> 2;
  const int nt = bx & 3;
  const int r0 = mt * 64;
  const int h0 = nt * 64;
  const bool isq = (r0 < BATCH * NO);
  const float* src = isq ? (q + (size_t)r0 * DIM)
                         : (k + (size_t)(r0 - BATCH * NO) * DIM);
  const int coff = isq ? 0 : DIM;

  float acc[4][4] = {};

  for (int c0 = 0; c0 < DIM; c0 += 32) {
    __syncthreads();
#pragma unroll
    for (int p = 0; p < 2; ++p) {
      int idx = p * 256 + t;
      int row = idx >> 3, j = idx & 7;
      float4 av = *(const float4*)(src + (size_t)row * DIM + c0 + j * 4);
      At[(4 * j + 0) * 68 + row] = av.x;
      At[(4 * j + 1) * 68 + row] = av.y;
      At[(4 * j + 2) * 68 + row] = av.z;
      At[(4 * j + 3) * 68 + row] = av.w;
      float4 wv = *(const float4*)(W1 + (size_t)(h0 + row) * (2 * DIM) + coff + c0 + j * 4);
      Wt[(4 * j + 0) * 68 + row] = wv.x;
      Wt[(4 * j + 1) * 68 + row] = wv.y;
      Wt[(4 * j + 2) * 68 + row] = wv.z;
      Wt[(4 * j + 3) * 68 + row] = wv.w;
    }
    __syncthreads();
#pragma unroll
    for (int dk = 0; dk < 32; ++dk) {
      float4 a4 = *(const float4*)&At[dk * 68 + ty * 4];
      float4 w4 = *(const float4*)&Wt[dk * 68 + tx * 4];
      const float ar[4] = {a4.x, a4.y, a4.z, a4.w};
      const float wr[4] = {w4.x, w4.y, w4.z, w4.w};
#pragma unroll
      for (int rr = 0; rr < 4; ++rr)
#pragma unroll
        for (int cc = 0; cc < 4; ++cc)
          acc[rr][cc] = fmaf(ar[rr], wr[cc], acc[rr][cc]);
    }
  }

  if (isq) {
    float4 bv = *(const float4*)(b1 + h0 + tx * 4);
    const float br[4] = {bv.x, bv.y, bv.z, bv.w};
#pragma unroll
    for (int rr = 0; rr < 4; ++rr) {
      int r = r0 + ty * 4 + rr;
      float4 ov;
      ov.x = (acc[rr][0] + br[0]) * CSCALE;
      ov.y = (acc[rr][1] + br[1]) * CSCALE;
      ov.z = (acc[rr][2] + br[2]) * CSCALE;
      ov.w = (acc[rr][3] + br[3]) * CSCALE;
      *(float4*)(qp + (size_t)r * DIM + h0 + tx * 4) = ov;
    }
  } else {
    // kp2 layout: float pairs (h even, h odd): kp2[((b*128 + h/2)*NI + i)*2 + (h&1)]
    int ig0 = r0 - BATCH * NO;
    int b  = ig0 >> 9;
    int i0 = (ig0 & 511) + ty * 4;          // multiple of 4
    int h2b = (h0 + tx * 4) >> 1;
#pragma unroll
    for (int c2 = 0; c2 < 2; ++c2) {
      size_t base = ((size_t)(b * 128 + h2b + c2) * NI + i0) * 2;
      float4 w0, w1;
      w0.x = acc[0][2 * c2]     * CSCALE;
      w0.y = acc[0][2 * c2 + 1] * CSCALE;
      w0.z = acc[1][2 * c2]     * CSCALE;
      w0.w = acc[1][2 * c2 + 1] * CSCALE;
      w1.x = acc[2][2 * c2]     * CSCALE;
      w1.y = acc[2][2 * c2 + 1] * CSCALE;
      w1.z = acc[3][2 * c2]     * CSCALE;
      w1.w = acc[3][2 * c2 + 1] * CSCALE;
      *(float4*)(kp2 + base)     = w0;
      *(float4*)(kp2 + base + 4) = w1;
    }
  }
}

__device__ __forceinline__ void f4arr(float4 v, float* a) {
  a[0] = v.x; a[1] = v.y; a[2] = v.z; a[3] = v.w;
}

// ---------------------------------------------------------------------------
// Kernel 2: one block (512 threads) per (b, o-pair). Grid 512 = 2 blocks/CU,
// 16 waves/CU (50% occupancy). XCD-swizzled: each XCD sees 2 b's (kp+v 2 MB).
// phase 1: thread = one i, 2 o's; kp2 float2 loads; q/W2 wave-uniform scalar
//          loads; algebraic tanh fold (exp2+rcp).
// phase 2: 2 softmaxes batched. phase 3: PV, v read once/block, partials LDS.
// phase 4: per-(d,o) thread dot with WfT column.
// ---------------------------------------------------------------------------
__global__ __launch_bounds__(512) void attn_kernel(
    const float* __restrict__ qp, const float* __restrict__ kp2,
    const float* __restrict__ v, const int* __restrict__ mask,
    const float* __restrict__ W2, const float* __restrict__ b2,
    const float* __restrict__ WfT, const float* __restrict__ bf,
    float* __restrict__ out, float* __restrict__ attn_out)
{
  __shared__ float sc[OT][NI];        // 4 KB
  __shared__ float pvp[8][OT][DIM];   // 16 KB
  __shared__ float o0[OT][DIM];       // 2 KB
  __shared__ float red4[8][OT];
  __shared__ float redw[8];

  const int t    = threadIdx.x;
  const int lane = t & 63;
  const int wid  = t >> 6;

  const int blk  = blockIdx.x;
  const int tile = (blk & 7) * 64 + (blk >> 3);   // XCD swizzle
  const int b    = tile >> 5;
  const int bo0  = b * 64 + (tile & 31) * OT;

  // ---- sumW2 (once per block) ----
  float partial = (t < DIM) ? W2[t] : 0.f;
#pragma unroll
  for (int off = 32; off >= 1; off >>= 1) partial += __shfl_xor(partial, off, 64);
  if (lane == 0) redw[wid] = partial;
  __syncthreads();
  float sumw2 = 0.f;
#pragma unroll
  for (int w = 0; w < 8; ++w) sumw2 += redw[w];
  const float base = sumw2 + b2[0];

  // ---- phase 1: scores s0,s1 for i = t ----
  const int i = t;
  const float2* kb = (const float2*)kp2 + (size_t)b * 128 * NI;
  const float* qrow0 = qp + (size_t)(bo0 + 0) * DIM;
  const float* qrow1 = qp + (size_t)(bo0 + 1) * DIM;

  float acc0 = 0.f, acc1 = 0.f;
#pragma unroll 2
  for (int h4 = 0; h4 < 64; ++h4) {
    float wr[4], q0[4], q1[4];
    f4arr(*(const float4*)(W2 + h4 * 4), wr);        // wave-uniform -> s_load
    f4arr(*(const float4*)(qrow0 + h4 * 4), q0);
    f4arr(*(const float4*)(qrow1 + h4 * 4), q1);
    float2 kva = kb[(size_t)(h4 * 2 + 0) * NI + i];
    float2 kvb = kb[(size_t)(h4 * 2 + 1) * NI + i];
    const float kv[4] = {kva.x, kva.y, kvb.x, kvb.y};
#pragma unroll
    for (int e = 0; e < 4; ++e) {
      float e0 = __builtin_amdgcn_exp2f(q0[e] + kv[e]);
      acc0 = fmaf(wr[e], __builtin_amdgcn_rcpf(e0 + 1.f), acc0);
      float e1 = __builtin_amdgcn_exp2f(q1[e] + kv[e]);
      acc1 = fmaf(wr[e], __builtin_amdgcn_rcpf(e1 + 1.f), acc1);
    }
  }

  const int mv = mask[(size_t)b * NI + i];
  float s0 = base - 2.f * acc0;
  float s1 = base - 2.f * acc1;
  if (mv) { s0 = -INFINITY; s1 = -INFINITY; }

  // ---- phase 2: 2 softmaxes over 512 lanes ----
  float m0 = s0, m1 = s1;
#pragma unroll
  for (int off = 32; off >= 1; off >>= 1) {
    m0 = fmaxf(m0, __shfl_xor(m0, off, 64));
    m1 = fmaxf(m1, __shfl_xor(m1, off, 64));
  }
  __syncthreads();     // redw reads done; red4 safe
  if (lane == 0) { red4[wid][0] = m0; red4[wid][1] = m1; }
  __syncthreads();
  m0 = red4[0][0]; m1 = red4[0][1];
#pragma unroll
  for (int w = 1; w < 8; ++w) {
    m0 = fmaxf(m0, red4[w][0]);
    m1 = fmaxf(m1, red4[w][1]);
  }

  float p0 = __expf(s0 - m0);
  float p1 = __expf(s1 - m1);
  float ps0 = p0, ps1 = p1;
#pragma unroll
  for (int off = 32; off >= 1; off >>= 1) {
    ps0 += __shfl_xor(ps0, off, 64);
    ps1 += __shfl_xor(ps1, off, 64);
  }
  __syncthreads();     // red4 (max) reads done
  if (lane == 0) { red4[wid][0] = ps0; red4[wid][1] = ps1; }
  __syncthreads();
  float ss0 = 0.f, ss1 = 0.f;
#pragma unroll
  for (int w = 0; w < 8; ++w) { ss0 += red4[w][0]; ss1 += red4[w][1]; }
  const float a0 = p0 * __builtin_amdgcn_rcpf(ss0);
  const float a1 = p1 * __builtin_amdgcn_rcpf(ss1);
  sc[0][i] = a0;
  sc[1][i] = a1;
  attn_out[(size_t)(bo0 + 0) * NI + i] = a0;
  attn_out[(size_t)(bo0 + 1) * NI + i] = a1;
  __syncthreads();

  // ---- phase 3: PV. wave wid: i in [wid*64, wid*64+64), lane = 4 d's ----
  {
    const int d4 = lane;
    float4 av0 = {0.f, 0.f, 0.f, 0.f};
    float4 av1 = {0.f, 0.f, 0.f, 0.f};
    const float4* vb4 = (const float4*)(v + (size_t)b * NI * DIM);
    for (int ib = wid * 64; ib < wid * 64 + 64; ib += 4) {
      float sa0[4], sa1[4];
      f4arr(*(const float4*)&sc[0][ib], sa0);
      f4arr(*(const float4*)&sc[1][ib], sa1);
#pragma unroll
      for (int j = 0; j < 4; ++j) {
        float4 vv = vb4[(size_t)(ib + j) * 64 + d4];
        av0.x = fmaf(sa0[j], vv.x, av0.x);
        av0.y = fmaf(sa0[j], vv.y, av0.y);
        av0.z = fmaf(sa0[j], vv.z, av0.z);
        av0.w = fmaf(sa0[j], vv.w, av0.w);
        av1.x = fmaf(sa1[j], vv.x, av1.x);
        av1.y = fmaf(sa1[j], vv.y, av1.y);
        av1.z = fmaf(sa1[j], vv.z, av1.z);
        av1.w = fmaf(sa1[j], vv.w, av1.w);
      }
    }
    *(float4*)&pvp[wid][0][d4 * 4] = av0;
    *(float4*)&pvp[wid][1][d4 * 4] = av1;
  }
  __syncthreads();
  {
    int oo = t >> 8, d = t & 255;
    float sacc = 0.f;
#pragma unroll
    for (int w = 0; w < 8; ++w) sacc += pvp[w][oo][d];
    o0[oo][d] = sacc;
  }
  __syncthreads();

  // ---- phase 4: out[d] = leaky(sum_e o0[e]*WfT[e][d] + bf[d]) ----
  {
    const int oo = t >> 8;
    const int d  = t & 255;
    float f = 0.f;
#pragma unroll 4
    for (int e4 = 0; e4 < 64; ++e4) {
      float oa[4];
      f4arr(*(const float4*)&o0[oo][e4 * 4], oa);
#pragma unroll
      for (int c = 0; c < 4; ++c)
        f = fmaf(oa[c], WfT[(size_t)(e4 * 4 + c) * DIM + d], f);
    }
    f += bf[d];
    f = (f >= 0.f) ? f : NEG_SLOPE * f;
    out[(size_t)(bo0 + oo) * DIM + d] = f;
  }
}

// ---------------------------------------------------------------------------
extern "C" void kernel_launch(void* const* d_in, const int* in_sizes, int n_in,
                              void* d_out, int out_size, void* d_ws, size_t ws_size,
                              hipStream_t stream) {
  const float* q    = (const float*)d_in[0];
  const float* k    = (const float*)d_in[1];
  const float* v    = (const float*)d_in[2];
  const int*   mask = (const int*)d_in[3];
  const float* W1   = (const float*)d_in[4];
  const float* b1   = (const float*)d_in[5];
  const float* W2   = (const float*)d_in[6];
  const float* b2   = (const float*)d_in[7];
  const float* Wf   = (const float*)d_in[8];
  const float* bf   = (const float*)d_in[9];

  float* out      = (float*)d_out;                    // (16,64,256)
  float* attn_out = out + (size_t)BATCH * NO * DIM;   // (16,64,512)

  float* qp  = (float*)d_ws;                          // 1024 x 256 (scaled, +b1)
  float* kp2 = qp + (size_t)BATCH * NO * DIM;         // 16 x 128 x 512 float2 (scaled)
  float* WfT = kp2 + (size_t)BATCH * DIM * NI;        // 256 x 256

  proj_kernel<<<592, 256, 0, stream>>>(q, k, W1, b1, Wf, qp, kp2, WfT);
  attn_kernel<<<(BATCH * NO) / OT, 512, 0, stream>>>(qp, kp2, v, mask, W2, b2,
                                                     WfT, bf, out, attn_out);
}